// Round 10
// baseline (500.270 us; speedup 1.0000x reference)
//
#include <hip/hip_runtime.h>
#include <hip/hip_bf16.h>
#include <math.h>

#define NEG_SLOPE 0.2f
#define CHUNK 6144         // edges staged per block in k_scatA

typedef short bf16x8 __attribute__((ext_vector_type(8)));
typedef float f32x4  __attribute__((ext_vector_type(4)));

__device__ __forceinline__ float leaky(float x){ return x > 0.f ? x : NEG_SLOPE*x; }
__device__ __forceinline__ float elu(float x){ return x > 0.f ? x : expm1f(x); }

__device__ __forceinline__ ushort f2bf(float f){
  uint u = __float_as_uint(f);
  u += 0x7fffu + ((u >> 16) & 1u);            // RNE
  return (ushort)(u >> 16);
}
__device__ __forceinline__ uint pk2(float lo, float hi){
  return (uint)f2bf(lo) | ((uint)f2bf(hi) << 16);
}
__device__ __forceinline__ float2 bfpair(uint v){   // uint = two packed bf16 (lo = even ch)
  return make_float2(__uint_as_float(v << 16), __uint_as_float(v & 0xffff0000u));
}

// ---------- CSR build: two-level bucketed counting sort ----------
__global__ __launch_bounds__(256) void k_histA(const int* __restrict__ ei, int E,
                                               int* __restrict__ bucketCount){
  __shared__ int hist[512];
  for (int b = threadIdx.x; b < 512; b += 256) hist[b] = 0;
  __syncthreads();
  int base = blockIdx.x * 2048;
  int cnt = min(2048, E - base);
  for (int i = threadIdx.x; i < cnt; i += 256)
    atomicAdd(&hist[ei[E + base + i] >> 8], 1);
  __syncthreads();
  for (int b = threadIdx.x; b < 512; b += 256)
    if (hist[b]) atomicAdd(&bucketCount[b], hist[b]);
}

__global__ __launch_bounds__(256) void k_scanB(const int* __restrict__ bucketCount, int NB,
                        int* __restrict__ bucketBase, int* __restrict__ gcursor, int E){
  __shared__ int s[512];
  for (int b = threadIdx.x; b < 512; b += 256)
    s[b] = (b < NB) ? bucketCount[b] : 0;
  __syncthreads();
  if (threadIdx.x == 0){
    int run = 0;
    for (int b = 0; b < NB; b++){ int v = s[b]; s[b] = run; run += v; }
  }
  __syncthreads();
  for (int b = threadIdx.x; b < NB; b += 256){
    bucketBase[b] = s[b]; gcursor[b] = s[b];
  }
  if (threadIdx.x == 0) bucketBase[NB] = E;
}

__global__ __launch_bounds__(256) void k_scatA(const int* __restrict__ ei, int E, int NB,
                         int* __restrict__ gcursor, uint* __restrict__ tmp){
  __shared__ uint stageS[CHUNK];
  __shared__ uint stageD[CHUNK];
  __shared__ int hist[512], pre[512], cur[512], gbase[512];
  __shared__ int scanArr[256];
  int tid = threadIdx.x;
  int base = blockIdx.x * CHUNK;
  int cnt = min(CHUNK, E - base);
  for (int b = tid; b < 512; b += 256) hist[b] = 0;
  __syncthreads();
  for (int i = tid; i < cnt; i += 256)
    atomicAdd(&hist[ei[E + base + i] >> 8], 1);
  __syncthreads();
  int a0 = hist[2*tid], a1 = hist[2*tid+1];
  scanArr[tid] = a0 + a1;
  __syncthreads();
  for (int st = 1; st < 256; st <<= 1){
    int v = (tid >= st) ? scanArr[tid - st] : 0;
    __syncthreads();
    scanArr[tid] += v;
    __syncthreads();
  }
  int eb = tid ? scanArr[tid-1] : 0;
  pre[2*tid] = eb;        cur[2*tid] = eb;
  pre[2*tid+1] = eb + a0; cur[2*tid+1] = eb + a0;
  if (2*tid < NB && a0 > 0)   gbase[2*tid]   = atomicAdd(&gcursor[2*tid],   a0);
  if (2*tid+1 < NB && a1 > 0) gbase[2*tid+1] = atomicAdd(&gcursor[2*tid+1], a1);
  __syncthreads();
  for (int i = tid; i < cnt; i += 256){
    int s = ei[base + i];
    int d = ei[E + base + i];
    int lpos = atomicAdd(&cur[d >> 8], 1);
    stageS[lpos] = (uint)s; stageD[lpos] = (uint)d;
  }
  __syncthreads();
  for (int i = tid; i < cnt; i += 256){
    uint d = stageD[i];
    int b = d >> 8;
    tmp[gbase[b] + (i - pre[b])] = (stageS[i] << 8) | (d & 255u);
  }
}

__global__ __launch_bounds__(256) void k_csr(const uint* __restrict__ tmp,
                      const int* __restrict__ bucketBase,
                      int N, int NB, int* __restrict__ offsets, int* __restrict__ csr){
  int b = blockIdx.x;
  int nodeBase = b << 8;
  int nNodes = min(256, N - nodeBase);
  int eBeg = bucketBase[b], eEnd = bucketBase[b+1];
  __shared__ int deg[256], cur[256];
  int tid = threadIdx.x;
  deg[tid] = 0;
  __syncthreads();
  for (int e = eBeg + tid; e < eEnd; e += 256)
    atomicAdd(&deg[tmp[e] & 255u], 1);
  __syncthreads();
  cur[tid] = deg[tid];
  __syncthreads();
  for (int st = 1; st < 256; st <<= 1){
    int w = (tid >= st) ? cur[tid - st] : 0;
    __syncthreads();
    cur[tid] += w;
    __syncthreads();
  }
  int excl = tid ? cur[tid-1] : 0;
  __syncthreads();
  cur[tid] = excl;
  if (tid < nNodes) offsets[nodeBase + tid] = eBeg + excl;
  if (b == NB-1 && tid == 0) offsets[N] = eEnd;
  __syncthreads();
  for (int e = eBeg + tid; e < eEnd; e += 256){
    uint u = tmp[e];
    int lpos = atomicAdd(&cur[u & 255u], 1);
    csr[eBeg + lpos] = (int)(u >> 8);
  }
}

// ---------- W repack: W[K=128][M=NT*16] fp32 -> B-fragment-ordered bf16 ----------
template<int NT>
__global__ __launch_bounds__(256) void k_wrep(const float* __restrict__ W, ushort* __restrict__ Wf){
  int idx = blockIdx.x*256 + threadIdx.x;
  if (idx >= NT*4*64) return;
  int lane = idx & 63;
  int c = (idx >> 6) & 3;
  int t = idx >> 8;
  int col = t*16 + (lane & 15);
  int k0 = c*32 + (lane >> 4)*8;
  uint4 o;
  const float* p0 = W + (size_t)k0*(NT*16) + col;
  o.x = pk2(p0[0],          p0[NT*16]);
  o.y = pk2(p0[2*NT*16],    p0[3*NT*16]);
  o.z = pk2(p0[4*NT*16],    p0[5*NT*16]);
  o.w = pk2(p0[6*NT*16],    p0[7*NT*16]);
  *(uint4*)(Wf + (size_t)idx*8) = o;
}

// ---------- MFMA GEMM: Y[n, NT*16](bf16) = X[n,128] @ W ----------
template<int NT, bool A_F32>
__global__ __launch_bounds__(256) void k_mgemm(const void* __restrict__ Xv,
                     const ushort* __restrict__ Wf, ushort* __restrict__ Y, int n){
  constexpr int M = NT*16;
  int lane = threadIdx.x & 63;
  int l15 = lane & 15, q = lane >> 4;
  int wgid = blockIdx.x*4 + (threadIdx.x >> 6);
  int nchunks = (n + 15) >> 4;
  int stride = gridDim.x*4;

  bf16x8 bw[NT][4];
  #pragma unroll
  for (int t = 0; t < NT; t++)
    #pragma unroll
    for (int c = 0; c < 4; c++)
      bw[t][c] = *(const bf16x8*)(Wf + (size_t)(((t<<2)+c)*64 + lane)*8);

  int chunk = wgid;
  if (chunk >= nchunks) return;

  bf16x8 aCur[4], aNext[4];
  auto loadA = [&](int ck, bf16x8* a){
    int m = ck*16 + l15;
    if (m >= n) m = n - 1;
    if (A_F32){
      const float* X = (const float*)Xv + (size_t)m*128 + q*8;
      #pragma unroll
      for (int c = 0; c < 4; c++){
        float4 u0 = *(const float4*)(X + c*32);
        float4 u1 = *(const float4*)(X + c*32 + 4);
        uint4 pkd;
        pkd.x = pk2(u0.x, u0.y); pkd.y = pk2(u0.z, u0.w);
        pkd.z = pk2(u1.x, u1.y); pkd.w = pk2(u1.z, u1.w);
        union { uint4 u; bf16x8 v; } cv; cv.u = pkd;
        a[c] = cv.v;
      }
    } else {
      const ushort* X = (const ushort*)Xv + (size_t)m*128 + q*8;
      #pragma unroll
      for (int c = 0; c < 4; c++) a[c] = *(const bf16x8*)(X + c*32);
    }
  };

  loadA(chunk, aCur);
  while (true){
    int nx = chunk + stride;
    if (nx < nchunks) loadA(nx, aNext);
    f32x4 acc[NT];
    #pragma unroll
    for (int t = 0; t < NT; t++) acc[t] = (f32x4){0.f,0.f,0.f,0.f};
    #pragma unroll
    for (int c = 0; c < 4; c++)
      #pragma unroll
      for (int t = 0; t < NT; t++)
        acc[t] = __builtin_amdgcn_mfma_f32_16x16x32_bf16(aCur[c], bw[t][c], acc[t], 0, 0, 0);
    int rowb = chunk*16 + q*4;
    #pragma unroll
    for (int t = 0; t < NT; t++)
      #pragma unroll
      for (int r = 0; r < 4; r++){
        int row = rowb + r;
        if (row < n) Y[(size_t)row*M + t*16 + l15] = f2bf(acc[t][r]);
      }
    if (nx >= nchunks) break;
    chunk = nx;
    #pragma unroll
    for (int c = 0; c < 4; c++) aCur[c] = aNext[c];
  }
}

// ---------- attention coefficients (reads bf16 h) ----------
__global__ __launch_bounds__(256) void k_attn(const ushort* __restrict__ Hb, const float* __restrict__ a_s,
                     const float* __restrict__ a_d, float* __restrict__ asrc, float* __restrict__ adst,
                     int n, int H, int M){
  int idx = blockIdx.x*256 + threadIdx.x;
  if (idx >= n*H) return;
  int node = idx / H, h = idx - node*H;
  const uint4* r4 = (const uint4*)(Hb + (size_t)node*M + h*32);
  const float* as = a_s + h*32;
  const float* ad = a_d + h*32;
  float s1 = 0.f, s2 = 0.f;
  #pragma unroll
  for (int i = 0; i < 4; i++){
    uint4 qv = r4[i];
    uint w[4] = {qv.x, qv.y, qv.z, qv.w};
    #pragma unroll
    for (int j = 0; j < 4; j++){
      float2 f = bfpair(w[j]);
      int c = i*8 + j*2;
      s1 += f.x*as[c] + f.y*as[c+1];
      s2 += f.x*ad[c] + f.y*ad[c+1];
    }
  }
  asrc[idx] = s1; adst[idx] = s2;
}

// ---------- FUSED per-dst aggregation, HC=128 (H=4), paired-edge lanes ----------
// One node per wave. Lane = (half = lane>>5: edge parity, lp = lane&31: channel quad ch=lp*4).
// Stage 64-edge chunks to LDS (1 exp per edge-head, coalesced csr load), then gather with
// uint2 (4-channel) loads: each VMEM instruction covers 2 edges (one per half).
// Final cross-half merge via shfl_xor(32). No barriers (same-wave LDS FIFO).
template<bool OUT_BF16>
__global__ __launch_bounds__(256) void k_agg128f(const ushort* __restrict__ Hb,
                    const float* __restrict__ asrc, const float* __restrict__ adst,
                    const int* __restrict__ offsets, const int* __restrict__ csr_src,
                    const float* __restrict__ bias, void* __restrict__ Out, int n){
  __shared__ float lwAll[4][256];     // 64 edge-slots x 4 heads per wave
  __shared__ int   lsAll[4][64];
  int wv = threadIdx.x >> 6;
  int lane = threadIdx.x & 63;
  float* lw = lwAll[wv];
  int*   ls = lsAll[wv];
  int node = blockIdx.x*4 + wv;
  if (node >= n) return;
  const int half = lane >> 5;
  const int lp = lane & 31;          // channels lp*4 .. lp*4+3
  const int h0 = lp >> 3;            // head for this channel quad
  const uint* rows = (const uint*)Hb;
  float4 adv = *(const float4*)(adst + (size_t)node*4);
  float adh = (h0==0)?adv.x:(h0==1)?adv.y:(h0==2)?adv.z:adv.w;
  float acc0=0.f, acc1=0.f, acc2=0.f, acc3=0.f, den=0.f;
  // self loop as pair (self, pad)
  {
    float w = (half == 0) ? __expf(leaky(asrc[(size_t)node*4 + h0] + adh)) : 0.f;
    uint2 r = *(const uint2*)(rows + (size_t)node*64 + lp*2);
    float2 fa = bfpair(r.x), fb = bfpair(r.y);
    den += w; acc0 += w*fa.x; acc1 += w*fa.y; acc2 += w*fb.x; acc3 += w*fb.y;
  }
  int j0 = offsets[node], end = offsets[node+1];
  for (int base = j0; base < end; base += 64){
    int m = min(64, end - base);
    if (lane < m){
      int s = csr_src[base + lane];
      ls[lane] = s;
      float4 a = *(const float4*)(asrc + (size_t)s*4);
      float4 w4;
      w4.x = __expf(leaky(a.x + adv.x));
      w4.y = __expf(leaky(a.y + adv.y));
      w4.z = __expf(leaky(a.z + adv.z));
      w4.w = __expf(leaky(a.w + adv.w));
      *(float4*)(lw + lane*4) = w4;
    }
    if (lane == m){                   // pad slot (only exists when m < 64; m<64 => lane can match)
      ls[m < 64 ? m : 0] = node;      // safe index
      if (m < 64) *(float4*)(lw + m*4) = make_float4(0.f,0.f,0.f,0.f);
    }
    int mp = (m + 1) & ~1;            // slots rounded to even (pad covers the odd tail)
    int e = 0;
    for (; e + 8 <= mp; e += 8){      // 4 pairs = 8 edges per iteration
      int e0 = e+half, e1 = e+2+half, e2 = e+4+half, e3 = e+6+half;
      int s0 = ls[e0], s1 = ls[e1], s2 = ls[e2], s3 = ls[e3];
      float w0 = lw[e0*4+h0], w1 = lw[e1*4+h0], w2 = lw[e2*4+h0], w3 = lw[e3*4+h0];
      uint2 r0 = *(const uint2*)(rows + (size_t)s0*64 + lp*2);
      uint2 r1 = *(const uint2*)(rows + (size_t)s1*64 + lp*2);
      uint2 r2 = *(const uint2*)(rows + (size_t)s2*64 + lp*2);
      uint2 r3 = *(const uint2*)(rows + (size_t)s3*64 + lp*2);
      float2 a0 = bfpair(r0.x), b0 = bfpair(r0.y);
      float2 a1 = bfpair(r1.x), b1 = bfpair(r1.y);
      float2 a2 = bfpair(r2.x), b2 = bfpair(r2.y);
      float2 a3 = bfpair(r3.x), b3 = bfpair(r3.y);
      den  += (w0 + w1) + (w2 + w3);
      acc0 += (w0*a0.x + w1*a1.x) + (w2*a2.x + w3*a3.x);
      acc1 += (w0*a0.y + w1*a1.y) + (w2*a2.y + w3*a3.y);
      acc2 += (w0*b0.x + w1*b1.x) + (w2*b2.x + w3*b3.x);
      acc3 += (w0*b0.y + w1*b1.y) + (w2*b2.y + w3*b3.y);
    }
    for (; e < mp; e += 2){
      int e0 = e + half;
      int s0 = ls[e0];
      float w0 = lw[e0*4+h0];
      uint2 r0 = *(const uint2*)(rows + (size_t)s0*64 + lp*2);
      float2 a0 = bfpair(r0.x), b0 = bfpair(r0.y);
      den += w0; acc0 += w0*a0.x; acc1 += w0*a0.y; acc2 += w0*b0.x; acc3 += w0*b0.y;
    }
  }
  // merge the two edge-parity halves (lane L <-> L^32 hold the same channels)
  den  += __shfl_xor(den, 32);
  acc0 += __shfl_xor(acc0, 32);
  acc1 += __shfl_xor(acc1, 32);
  acc2 += __shfl_xor(acc2, 32);
  acc3 += __shfl_xor(acc3, 32);
  if (half == 0){
    float inv = 1.f/(den + 1e-16f);
    int ch = lp*4;
    float4 bv = *(const float4*)(bias + ch);
    float o0 = elu(acc0*inv + bv.x);
    float o1 = elu(acc1*inv + bv.y);
    float o2 = elu(acc2*inv + bv.z);
    float o3 = elu(acc3*inv + bv.w);
    if (OUT_BF16){
      uint2 o; o.x = pk2(o0, o1); o.y = pk2(o2, o3);
      *(uint2*)((uint*)Out + (size_t)node*64 + lp*2) = o;
    } else {
      *(float4*)((float*)Out + (size_t)node*128 + ch) = make_float4(o0, o1, o2, o3);
    }
  }
}

// ---------- per-dst aggregation HC=32 (H=1), fused weights via LDS staging ----------
// 4 nodes per wave (group g = lane>>4, i = lane&15). Stage 16-edge chunks per node:
// lane i computes 1 exp per edge; inner loop broadcasts from LDS. Pad slots carry w=0.
__global__ __launch_bounds__(256) void k_agg32(const ushort* __restrict__ Hb,
                    const float* __restrict__ asrc, const float* __restrict__ adst,
                    const int* __restrict__ offsets, const int* __restrict__ csr_src,
                    const float* __restrict__ bias, float* __restrict__ Out, int n){
  __shared__ int   lsAll[4][4][16];
  __shared__ float lwAll[4][4][16];
  int wv = threadIdx.x >> 6;
  int lane = threadIdx.x & 63;
  int g = lane >> 4, i = lane & 15;
  int node = (blockIdx.x*4 + wv)*4 + g;
  if (node >= n) return;
  int* ls = lsAll[wv][g];
  float* lw = lwAll[wv][g];
  const uint* rows = (const uint*)Hb;
  float adn = adst[node];
  float acc0 = 0.f, acc1 = 0.f, den = 0.f;
  // self loop
  {
    float w = __expf(leaky(asrc[node] + adn));
    float2 f = bfpair(rows[(size_t)node*16 + i]);
    den += w; acc0 += w*f.x; acc1 += w*f.y;
  }
  int j0 = offsets[node], end = offsets[node+1];
  for (int base = j0; base < end; base += 16){
    int m = min(16, end - base);
    {
      int idx = base + i;
      bool v = idx < end;
      int s = v ? csr_src[idx] : node;
      ls[i] = s;
      lw[i] = v ? __expf(leaky(asrc[s] + adn)) : 0.f;
    }
    int mR = (m + 3) & ~3;
    for (int e = 0; e < mR; e += 4){
      int s0 = ls[e], s1 = ls[e+1], s2 = ls[e+2], s3 = ls[e+3];
      float w0 = lw[e], w1 = lw[e+1], w2 = lw[e+2], w3 = lw[e+3];
      uint r0 = rows[(size_t)s0*16 + i];
      uint r1 = rows[(size_t)s1*16 + i];
      uint r2 = rows[(size_t)s2*16 + i];
      uint r3 = rows[(size_t)s3*16 + i];
      float2 f0 = bfpair(r0), f1 = bfpair(r1), f2 = bfpair(r2), f3 = bfpair(r3);
      den  += (w0 + w1) + (w2 + w3);
      acc0 += w0*f0.x + w1*f1.x + w2*f2.x + w3*f3.x;
      acc1 += w0*f0.y + w1*f1.y + w2*f2.y + w3*f3.y;
    }
  }
  float inv = 1.f/(den + 1e-16f);
  int ch = i*2;
  float2 o;
  o.x = elu(acc0*inv + bias[ch]);
  o.y = elu(acc1*inv + bias[ch+1]);
  *(float2*)(Out + (size_t)node*32 + ch) = o;
}

// ---------- readout ----------
__global__ __launch_bounds__(256) void k_bounds(const int* __restrict__ batch, int n, int G,
                                                int* __restrict__ gstart){
  int i = blockIdx.x*256 + threadIdx.x;
  if (i >= n) return;
  int b = batch[i];
  int bp = (i > 0) ? batch[i-1] : -1;
  for (int g = bp + 1; g <= b; g++) gstart[g] = i;
  if (i == n-1){
    for (int g = b + 1; g <= G; g++) gstart[g] = n;
  }
}

__global__ __launch_bounds__(256) void k_pool2(const float* __restrict__ H3,
                     const int* __restrict__ gstart, const float* __restrict__ fcw,
                     const float* __restrict__ fcb, float* __restrict__ out, int G){
  int g = blockIdx.x;
  int s0 = gstart[g], s1 = gstart[g+1];
  int tid = threadIdx.x;
  int c = tid & 31, r = tid >> 5;
  float sum = 0.f;
  for (int i = s0 + r; i < s1; i += 8)
    sum += H3[(size_t)i*32 + c];
  __shared__ float sh[8][32];
  sh[r][c] = sum;
  __syncthreads();
  if (tid < 32){
    float t = 0.f;
    #pragma unroll
    for (int k = 0; k < 8; k++) t += sh[k][tid];
    t *= fcw[tid];
    #pragma unroll
    for (int off = 16; off; off >>= 1) t += __shfl_down(t, off, 32);
    if (tid == 0){
      float cnt = (float)(s1 - s0); if (cnt < 1.f) cnt = 1.f;
      out[g] = t/cnt + fcb[0];
    }
  }
}

extern "C" void kernel_launch(void* const* d_in, const int* in_sizes, int n_in,
                              void* d_out, int out_size, void* d_ws, size_t ws_size,
                              hipStream_t stream){
  const float* x    = (const float*)d_in[0];
  const int*   ei   = (const int*)d_in[1];
  const int*   batch= (const int*)d_in[2];
  const float* W1   = (const float*)d_in[3];
  const float* as1  = (const float*)d_in[4];
  const float* ad1  = (const float*)d_in[5];
  const float* b1   = (const float*)d_in[6];
  const float* W2   = (const float*)d_in[7];
  const float* as2  = (const float*)d_in[8];
  const float* ad2  = (const float*)d_in[9];
  const float* b2   = (const float*)d_in[10];
  const float* W3   = (const float*)d_in[11];
  const float* as3  = (const float*)d_in[12];
  const float* ad3  = (const float*)d_in[13];
  const float* b3   = (const float*)d_in[14];
  const float* fcw  = (const float*)d_in[15];
  const float* fcb  = (const float*)d_in[16];
  float* out = (float*)d_out;

  const int N = in_sizes[0] / 128;
  const int E = in_sizes[1] / 2;
  const int G = out_size;
  const int NB = (N + 255) >> 8;

  char* p = (char*)d_ws;
  auto alloc = [&](size_t bytes) -> void* {
    void* r = (void*)p;
    p += (bytes + 255) & ~(size_t)255;
    return r;
  };
  ushort* bufH   = (ushort*)alloc((size_t)N*128*sizeof(ushort));  // GEMM out (bf16)
  ushort* aggB   = (ushort*)alloc((size_t)N*128*sizeof(ushort));  // agg out L1/L2 (bf16)
  float*  bufA32 = (float*)alloc((size_t)N*32*sizeof(float));     // agg out L3 (fp32)
  float*  asrc   = (float*)alloc((size_t)N*4*sizeof(float));
  float*  adst   = (float*)alloc((size_t)N*4*sizeof(float));
  int*    offsets= (int*)alloc((size_t)(N+1)*sizeof(int));
  int*    csr    = (int*)alloc((size_t)E*sizeof(int));
  uint*   tmp    = (uint*)alloc((size_t)E*sizeof(uint));
  int*    bCount = (int*)alloc(512*sizeof(int));
  int*    bBase  = (int*)alloc(520*sizeof(int));
  int*    gcursor= (int*)alloc(512*sizeof(int));
  int*    gstart = (int*)alloc((size_t)(G+1)*sizeof(int));
  ushort* Wf1    = (ushort*)alloc(8*4*64*8*sizeof(ushort));
  ushort* Wf2    = (ushort*)alloc(8*4*64*8*sizeof(ushort));
  ushort* Wf3    = (ushort*)alloc(2*4*64*8*sizeof(ushort));

  hipMemsetAsync(bCount, 0, 512*sizeof(int), stream);

  // W repacks (independent, cheap)
  k_wrep<8><<<8, 256, 0, stream>>>(W1, Wf1);
  k_wrep<8><<<8, 256, 0, stream>>>(W2, Wf2);
  k_wrep<2><<<2, 256, 0, stream>>>(W3, Wf3);

  // CSR build
  k_histA<<<(E+2047)/2048, 256, 0, stream>>>(ei, E, bCount);
  k_scanB<<<1, 256, 0, stream>>>(bCount, NB, bBase, gcursor, E);
  k_scatA<<<(E+CHUNK-1)/CHUNK, 256, 0, stream>>>(ei, E, NB, gcursor, tmp);
  k_csr<<<NB, 256, 0, stream>>>(tmp, bBase, N, NB, offsets, csr);
  k_bounds<<<(N+255)/256, 256, 0, stream>>>(batch, N, G, gstart);

  const int GB = 512;
  const int NWB = (N + 3)/4;      // fused agg128: 4 nodes/block (1 per wave)
  const int NWB32 = (N + 15)/16;  // agg32: 16 nodes/block (4 per wave)
  // layer 1
  k_mgemm<8, true ><<<GB, 256, 0, stream>>>(x, Wf1, bufH, N);
  k_attn<<<(N*4+255)/256, 256, 0, stream>>>(bufH, as1, ad1, asrc, adst, N, 4, 128);
  k_agg128f<true><<<NWB, 256, 0, stream>>>(bufH, asrc, adst, offsets, csr, b1, aggB, N);
  // layer 2
  k_mgemm<8, false><<<GB, 256, 0, stream>>>(aggB, Wf2, bufH, N);
  k_attn<<<(N*4+255)/256, 256, 0, stream>>>(bufH, as2, ad2, asrc, adst, N, 4, 128);
  k_agg128f<true><<<NWB, 256, 0, stream>>>(bufH, asrc, adst, offsets, csr, b2, aggB, N);
  // layer 3
  k_mgemm<2, false><<<GB, 256, 0, stream>>>(aggB, Wf3, bufH, N);
  k_attn<<<(N+255)/256, 256, 0, stream>>>(bufH, as3, ad3, asrc, adst, N, 1, 32);
  k_agg32<<<NWB32, 256, 0, stream>>>(bufH, asrc, adst, offsets, csr, b3, bufA32, N);
  // readout
  k_pool2<<<G, 256, 0, stream>>>(bufA32, gstart, fcw, fcb, out, G);
}

// Round 11
// 460.863 us; speedup vs baseline: 1.0855x; 1.0855x over previous
//
#include <hip/hip_runtime.h>
#include <hip/hip_bf16.h>
#include <math.h>

#define NEG_SLOPE 0.2f
#define CHUNK 6144         // edges staged per block in k_scatA

typedef short bf16x8 __attribute__((ext_vector_type(8)));
typedef float f32x4  __attribute__((ext_vector_type(4)));

__device__ __forceinline__ float leaky(float x){ return x > 0.f ? x : NEG_SLOPE*x; }
__device__ __forceinline__ float elu(float x){ return x > 0.f ? x : expm1f(x); }

__device__ __forceinline__ ushort f2bf(float f){
  uint u = __float_as_uint(f);
  u += 0x7fffu + ((u >> 16) & 1u);            // RNE
  return (ushort)(u >> 16);
}
__device__ __forceinline__ uint pk2(float lo, float hi){
  return (uint)f2bf(lo) | ((uint)f2bf(hi) << 16);
}
__device__ __forceinline__ float2 bfpair(uint v){   // uint = two packed bf16 (lo = even ch)
  return make_float2(__uint_as_float(v << 16), __uint_as_float(v & 0xffff0000u));
}

// ---------- CSR build: two-level bucketed counting sort ----------
__global__ __launch_bounds__(256) void k_histA(const int* __restrict__ ei, int E,
                                               int* __restrict__ bucketCount){
  __shared__ int hist[512];
  for (int b = threadIdx.x; b < 512; b += 256) hist[b] = 0;
  __syncthreads();
  int base = blockIdx.x * 2048;
  int cnt = min(2048, E - base);
  for (int i = threadIdx.x; i < cnt; i += 256)
    atomicAdd(&hist[ei[E + base + i] >> 8], 1);
  __syncthreads();
  for (int b = threadIdx.x; b < 512; b += 256)
    if (hist[b]) atomicAdd(&bucketCount[b], hist[b]);
}

__global__ __launch_bounds__(256) void k_scanB(const int* __restrict__ bucketCount, int NB,
                        int* __restrict__ bucketBase, int* __restrict__ gcursor, int E){
  __shared__ int s[512];
  for (int b = threadIdx.x; b < 512; b += 256)
    s[b] = (b < NB) ? bucketCount[b] : 0;
  __syncthreads();
  if (threadIdx.x == 0){
    int run = 0;
    for (int b = 0; b < NB; b++){ int v = s[b]; s[b] = run; run += v; }
  }
  __syncthreads();
  for (int b = threadIdx.x; b < NB; b += 256){
    bucketBase[b] = s[b]; gcursor[b] = s[b];
  }
  if (threadIdx.x == 0) bucketBase[NB] = E;
}

__global__ __launch_bounds__(256) void k_scatA(const int* __restrict__ ei, int E, int NB,
                         int* __restrict__ gcursor, uint* __restrict__ tmp){
  __shared__ uint stageS[CHUNK];
  __shared__ uint stageD[CHUNK];
  __shared__ int hist[512], pre[512], cur[512], gbase[512];
  __shared__ int scanArr[256];
  int tid = threadIdx.x;
  int base = blockIdx.x * CHUNK;
  int cnt = min(CHUNK, E - base);
  for (int b = tid; b < 512; b += 256) hist[b] = 0;
  __syncthreads();
  for (int i = tid; i < cnt; i += 256)
    atomicAdd(&hist[ei[E + base + i] >> 8], 1);
  __syncthreads();
  int a0 = hist[2*tid], a1 = hist[2*tid+1];
  scanArr[tid] = a0 + a1;
  __syncthreads();
  for (int st = 1; st < 256; st <<= 1){
    int v = (tid >= st) ? scanArr[tid - st] : 0;
    __syncthreads();
    scanArr[tid] += v;
    __syncthreads();
  }
  int eb = tid ? scanArr[tid-1] : 0;
  pre[2*tid] = eb;        cur[2*tid] = eb;
  pre[2*tid+1] = eb + a0; cur[2*tid+1] = eb + a0;
  if (2*tid < NB && a0 > 0)   gbase[2*tid]   = atomicAdd(&gcursor[2*tid],   a0);
  if (2*tid+1 < NB && a1 > 0) gbase[2*tid+1] = atomicAdd(&gcursor[2*tid+1], a1);
  __syncthreads();
  for (int i = tid; i < cnt; i += 256){
    int s = ei[base + i];
    int d = ei[E + base + i];
    int lpos = atomicAdd(&cur[d >> 8], 1);
    stageS[lpos] = (uint)s; stageD[lpos] = (uint)d;
  }
  __syncthreads();
  for (int i = tid; i < cnt; i += 256){
    uint d = stageD[i];
    int b = d >> 8;
    tmp[gbase[b] + (i - pre[b])] = (stageS[i] << 8) | (d & 255u);
  }
}

__global__ __launch_bounds__(256) void k_csr(const uint* __restrict__ tmp,
                      const int* __restrict__ bucketBase,
                      int N, int NB, int* __restrict__ offsets, int* __restrict__ csr){
  int b = blockIdx.x;
  int nodeBase = b << 8;
  int nNodes = min(256, N - nodeBase);
  int eBeg = bucketBase[b], eEnd = bucketBase[b+1];
  __shared__ int deg[256], cur[256];
  int tid = threadIdx.x;
  deg[tid] = 0;
  __syncthreads();
  for (int e = eBeg + tid; e < eEnd; e += 256)
    atomicAdd(&deg[tmp[e] & 255u], 1);
  __syncthreads();
  cur[tid] = deg[tid];
  __syncthreads();
  for (int st = 1; st < 256; st <<= 1){
    int w = (tid >= st) ? cur[tid - st] : 0;
    __syncthreads();
    cur[tid] += w;
    __syncthreads();
  }
  int excl = tid ? cur[tid-1] : 0;
  __syncthreads();
  cur[tid] = excl;
  if (tid < nNodes) offsets[nodeBase + tid] = eBeg + excl;
  if (b == NB-1 && tid == 0) offsets[N] = eEnd;
  __syncthreads();
  for (int e = eBeg + tid; e < eEnd; e += 256){
    uint u = tmp[e];
    int lpos = atomicAdd(&cur[u & 255u], 1);
    csr[eBeg + lpos] = (int)(u >> 8);
  }
}

// ---------- W repack: W[K=128][M=NT*16] fp32 -> B-fragment-ordered bf16 ----------
template<int NT>
__global__ __launch_bounds__(256) void k_wrep(const float* __restrict__ W, ushort* __restrict__ Wf){
  int idx = blockIdx.x*256 + threadIdx.x;
  if (idx >= NT*4*64) return;
  int lane = idx & 63;
  int c = (idx >> 6) & 3;
  int t = idx >> 8;
  int col = t*16 + (lane & 15);
  int k0 = c*32 + (lane >> 4)*8;
  uint4 o;
  const float* p0 = W + (size_t)k0*(NT*16) + col;
  o.x = pk2(p0[0],          p0[NT*16]);
  o.y = pk2(p0[2*NT*16],    p0[3*NT*16]);
  o.z = pk2(p0[4*NT*16],    p0[5*NT*16]);
  o.w = pk2(p0[6*NT*16],    p0[7*NT*16]);
  *(uint4*)(Wf + (size_t)idx*8) = o;
}

// ---------- MFMA GEMM: Y[n, NT*16](bf16) = X[n,128] @ W ----------
template<int NT, bool A_F32>
__global__ __launch_bounds__(256) void k_mgemm(const void* __restrict__ Xv,
                     const ushort* __restrict__ Wf, ushort* __restrict__ Y, int n){
  constexpr int M = NT*16;
  int lane = threadIdx.x & 63;
  int l15 = lane & 15, q = lane >> 4;
  int wgid = blockIdx.x*4 + (threadIdx.x >> 6);
  int nchunks = (n + 15) >> 4;
  int stride = gridDim.x*4;

  bf16x8 bw[NT][4];
  #pragma unroll
  for (int t = 0; t < NT; t++)
    #pragma unroll
    for (int c = 0; c < 4; c++)
      bw[t][c] = *(const bf16x8*)(Wf + (size_t)(((t<<2)+c)*64 + lane)*8);

  int chunk = wgid;
  if (chunk >= nchunks) return;

  bf16x8 aCur[4], aNext[4];
  auto loadA = [&](int ck, bf16x8* a){
    int m = ck*16 + l15;
    if (m >= n) m = n - 1;
    if (A_F32){
      const float* X = (const float*)Xv + (size_t)m*128 + q*8;
      #pragma unroll
      for (int c = 0; c < 4; c++){
        float4 u0 = *(const float4*)(X + c*32);
        float4 u1 = *(const float4*)(X + c*32 + 4);
        uint4 pkd;
        pkd.x = pk2(u0.x, u0.y); pkd.y = pk2(u0.z, u0.w);
        pkd.z = pk2(u1.x, u1.y); pkd.w = pk2(u1.z, u1.w);
        union { uint4 u; bf16x8 v; } cv; cv.u = pkd;
        a[c] = cv.v;
      }
    } else {
      const ushort* X = (const ushort*)Xv + (size_t)m*128 + q*8;
      #pragma unroll
      for (int c = 0; c < 4; c++) a[c] = *(const bf16x8*)(X + c*32);
    }
  };

  loadA(chunk, aCur);
  while (true){
    int nx = chunk + stride;
    if (nx < nchunks) loadA(nx, aNext);
    f32x4 acc[NT];
    #pragma unroll
    for (int t = 0; t < NT; t++) acc[t] = (f32x4){0.f,0.f,0.f,0.f};
    #pragma unroll
    for (int c = 0; c < 4; c++)
      #pragma unroll
      for (int t = 0; t < NT; t++)
        acc[t] = __builtin_amdgcn_mfma_f32_16x16x32_bf16(aCur[c], bw[t][c], acc[t], 0, 0, 0);
    int rowb = chunk*16 + q*4;
    #pragma unroll
    for (int t = 0; t < NT; t++)
      #pragma unroll
      for (int r = 0; r < 4; r++){
        int row = rowb + r;
        if (row < n) Y[(size_t)row*M + t*16 + l15] = f2bf(acc[t][r]);
      }
    if (nx >= nchunks) break;
    chunk = nx;
    #pragma unroll
    for (int c = 0; c < 4; c++) aCur[c] = aNext[c];
  }
}

// ---------- attention coefficients (reads bf16 h) ----------
__global__ __launch_bounds__(256) void k_attn(const ushort* __restrict__ Hb, const float* __restrict__ a_s,
                     const float* __restrict__ a_d, float* __restrict__ asrc, float* __restrict__ adst,
                     int n, int H, int M){
  int idx = blockIdx.x*256 + threadIdx.x;
  if (idx >= n*H) return;
  int node = idx / H, h = idx - node*H;
  const uint4* r4 = (const uint4*)(Hb + (size_t)node*M + h*32);
  const float* as = a_s + h*32;
  const float* ad = a_d + h*32;
  float s1 = 0.f, s2 = 0.f;
  #pragma unroll
  for (int i = 0; i < 4; i++){
    uint4 qv = r4[i];
    uint w[4] = {qv.x, qv.y, qv.z, qv.w};
    #pragma unroll
    for (int j = 0; j < 4; j++){
      float2 f = bfpair(w[j]);
      int c = i*8 + j*2;
      s1 += f.x*as[c] + f.y*as[c+1];
      s2 += f.x*ad[c] + f.y*ad[c+1];
    }
  }
  asrc[idx] = s1; adst[idx] = s2;
}

// ---------- FUSED per-dst aggregation for HC=128 (H=4) ----------
// One node per wave (R9-proven shape: VGPR 32, occupancy ~72%).
// 64-edge chunks: stage (coalesced csr + random asrc + 4 exps/lane -> LDS),
// then 8-way-unrolled gather with LDS-broadcast weights/indices. No barriers:
// same-wave LDS producer/consumer ordered by lgkmcnt (per-wave FIFO).
template<bool OUT_BF16>
__global__ __launch_bounds__(256) void k_agg128f(const ushort* __restrict__ Hb,
                    const float* __restrict__ asrc, const float* __restrict__ adst,
                    const int* __restrict__ offsets, const int* __restrict__ csr_src,
                    const float* __restrict__ bias, void* __restrict__ Out, int n){
  __shared__ float lwAll[4][256];     // 64 edges x 4 heads per wave
  __shared__ int   lsAll[4][64];
  int wv = threadIdx.x >> 6;
  int lane = threadIdx.x & 63;
  float* lw = lwAll[wv];
  int*   ls = lsAll[wv];
  int node = blockIdx.x*4 + wv;
  if (node >= n) return;
  const int up = lane, ch = up*2, h0 = up >> 4;
  const uint* rows = (const uint*)Hb;
  float4 adv = *(const float4*)(adst + (size_t)node*4);
  float adh = (h0==0)?adv.x:(h0==1)?adv.y:(h0==2)?adv.z:adv.w;
  float acc0 = 0.f, acc1 = 0.f, den = 0.f;
  // self loop
  {
    float w = __expf(leaky(asrc[(size_t)node*4 + h0] + adh));
    float2 f = bfpair(rows[(size_t)node*64 + up]);
    den += w; acc0 += w*f.x; acc1 += w*f.y;
  }
  int j0 = offsets[node], end = offsets[node+1];
  for (int base = j0; base < end; base += 64){
    int m = min(64, end - base);
    if (lane < m){
      int s = csr_src[base + lane];
      ls[lane] = s;
      float4 a = *(const float4*)(asrc + (size_t)s*4);
      float4 w4;
      w4.x = __expf(leaky(a.x + adv.x));
      w4.y = __expf(leaky(a.y + adv.y));
      w4.z = __expf(leaky(a.z + adv.z));
      w4.w = __expf(leaky(a.w + adv.w));
      *(float4*)(lw + lane*4) = w4;
    }
    int e = 0;
    for (; e + 8 <= m; e += 8){
      int s0=ls[e+0], s1=ls[e+1], s2=ls[e+2], s3=ls[e+3];
      int s4=ls[e+4], s5=ls[e+5], s6=ls[e+6], s7=ls[e+7];
      float w0=lw[(e+0)*4+h0], w1=lw[(e+1)*4+h0], w2=lw[(e+2)*4+h0], w3=lw[(e+3)*4+h0];
      float w4=lw[(e+4)*4+h0], w5=lw[(e+5)*4+h0], w6=lw[(e+6)*4+h0], w7=lw[(e+7)*4+h0];
      uint r0 = rows[(size_t)s0*64 + up];
      uint r1 = rows[(size_t)s1*64 + up];
      uint r2 = rows[(size_t)s2*64 + up];
      uint r3 = rows[(size_t)s3*64 + up];
      uint r4 = rows[(size_t)s4*64 + up];
      uint r5 = rows[(size_t)s5*64 + up];
      uint r6 = rows[(size_t)s6*64 + up];
      uint r7 = rows[(size_t)s7*64 + up];
      float2 f0=bfpair(r0), f1=bfpair(r1), f2=bfpair(r2), f3=bfpair(r3);
      float2 f4=bfpair(r4), f5=bfpair(r5), f6=bfpair(r6), f7=bfpair(r7);
      den  += ((w0+w1)+(w2+w3)) + ((w4+w5)+(w6+w7));
      acc0 += (w0*f0.x + w1*f1.x + w2*f2.x + w3*f3.x)
            + (w4*f4.x + w5*f5.x + w6*f6.x + w7*f7.x);
      acc1 += (w0*f0.y + w1*f1.y + w2*f2.y + w3*f3.y)
            + (w4*f4.y + w5*f5.y + w6*f6.y + w7*f7.y);
    }
    for (; e < m; e++){
      int s = ls[e];
      float w = lw[e*4 + h0];
      float2 f = bfpair(rows[(size_t)s*64 + up]);
      den += w; acc0 += w*f.x; acc1 += w*f.y;
    }
  }
  float inv = 1.f/(den + 1e-16f);
  float ox = elu(acc0*inv + bias[ch]);
  float oy = elu(acc1*inv + bias[ch+1]);
  if (OUT_BF16){
    ((uint*)Out)[(size_t)node*64 + up] = pk2(ox, oy);
  } else {
    *(float2*)((float*)Out + (size_t)node*128 + ch) = make_float2(ox, oy);
  }
}

// ---------- per-dst aggregation HC=32 (H=1), fused weights via LDS staging ----------
// 4 nodes per wave (group g = lane>>4, i = lane&15). Stage 16-edge chunks per node:
// lane i computes 1 exp per edge; inner loop broadcasts from LDS. Pad slots carry w=0.
__global__ __launch_bounds__(256) void k_agg32(const ushort* __restrict__ Hb,
                    const float* __restrict__ asrc, const float* __restrict__ adst,
                    const int* __restrict__ offsets, const int* __restrict__ csr_src,
                    const float* __restrict__ bias, float* __restrict__ Out, int n){
  __shared__ int   lsAll[4][4][16];
  __shared__ float lwAll[4][4][16];
  int wv = threadIdx.x >> 6;
  int lane = threadIdx.x & 63;
  int g = lane >> 4, i = lane & 15;
  int node = (blockIdx.x*4 + wv)*4 + g;
  if (node >= n) return;
  int* ls = lsAll[wv][g];
  float* lw = lwAll[wv][g];
  const uint* rows = (const uint*)Hb;
  float adn = adst[node];
  float acc0 = 0.f, acc1 = 0.f, den = 0.f;
  // self loop
  {
    float w = __expf(leaky(asrc[node] + adn));
    float2 f = bfpair(rows[(size_t)node*16 + i]);
    den += w; acc0 += w*f.x; acc1 += w*f.y;
  }
  int j0 = offsets[node], end = offsets[node+1];
  for (int base = j0; base < end; base += 16){
    int m = min(16, end - base);
    {
      int idx = base + i;
      bool v = idx < end;
      int s = v ? csr_src[idx] : node;
      ls[i] = s;
      lw[i] = v ? __expf(leaky(asrc[s] + adn)) : 0.f;
    }
    int mR = (m + 3) & ~3;
    for (int e = 0; e < mR; e += 4){
      int s0 = ls[e], s1 = ls[e+1], s2 = ls[e+2], s3 = ls[e+3];
      float w0 = lw[e], w1 = lw[e+1], w2 = lw[e+2], w3 = lw[e+3];
      uint r0 = rows[(size_t)s0*16 + i];
      uint r1 = rows[(size_t)s1*16 + i];
      uint r2 = rows[(size_t)s2*16 + i];
      uint r3 = rows[(size_t)s3*16 + i];
      float2 f0 = bfpair(r0), f1 = bfpair(r1), f2 = bfpair(r2), f3 = bfpair(r3);
      den  += (w0 + w1) + (w2 + w3);
      acc0 += w0*f0.x + w1*f1.x + w2*f2.x + w3*f3.x;
      acc1 += w0*f0.y + w1*f1.y + w2*f2.y + w3*f3.y;
    }
  }
  float inv = 1.f/(den + 1e-16f);
  int ch = i*2;
  float2 o;
  o.x = elu(acc0*inv + bias[ch]);
  o.y = elu(acc1*inv + bias[ch+1]);
  *(float2*)(Out + (size_t)node*32 + ch) = o;
}

// ---------- readout ----------
__global__ __launch_bounds__(256) void k_bounds(const int* __restrict__ batch, int n, int G,
                                                int* __restrict__ gstart){
  int i = blockIdx.x*256 + threadIdx.x;
  if (i >= n) return;
  int b = batch[i];
  int bp = (i > 0) ? batch[i-1] : -1;
  for (int g = bp + 1; g <= b; g++) gstart[g] = i;
  if (i == n-1){
    for (int g = b + 1; g <= G; g++) gstart[g] = n;
  }
}

__global__ __launch_bounds__(256) void k_pool2(const float* __restrict__ H3,
                     const int* __restrict__ gstart, const float* __restrict__ fcw,
                     const float* __restrict__ fcb, float* __restrict__ out, int G){
  int g = blockIdx.x;
  int s0 = gstart[g], s1 = gstart[g+1];
  int tid = threadIdx.x;
  int c = tid & 31, r = tid >> 5;
  float sum = 0.f;
  for (int i = s0 + r; i < s1; i += 8)
    sum += H3[(size_t)i*32 + c];
  __shared__ float sh[8][32];
  sh[r][c] = sum;
  __syncthreads();
  if (tid < 32){
    float t = 0.f;
    #pragma unroll
    for (int k = 0; k < 8; k++) t += sh[k][tid];
    t *= fcw[tid];
    #pragma unroll
    for (int off = 16; off; off >>= 1) t += __shfl_down(t, off, 32);
    if (tid == 0){
      float cnt = (float)(s1 - s0); if (cnt < 1.f) cnt = 1.f;
      out[g] = t/cnt + fcb[0];
    }
  }
}

extern "C" void kernel_launch(void* const* d_in, const int* in_sizes, int n_in,
                              void* d_out, int out_size, void* d_ws, size_t ws_size,
                              hipStream_t stream){
  const float* x    = (const float*)d_in[0];
  const int*   ei   = (const int*)d_in[1];
  const int*   batch= (const int*)d_in[2];
  const float* W1   = (const float*)d_in[3];
  const float* as1  = (const float*)d_in[4];
  const float* ad1  = (const float*)d_in[5];
  const float* b1   = (const float*)d_in[6];
  const float* W2   = (const float*)d_in[7];
  const float* as2  = (const float*)d_in[8];
  const float* ad2  = (const float*)d_in[9];
  const float* b2   = (const float*)d_in[10];
  const float* W3   = (const float*)d_in[11];
  const float* as3  = (const float*)d_in[12];
  const float* ad3  = (const float*)d_in[13];
  const float* b3   = (const float*)d_in[14];
  const float* fcw  = (const float*)d_in[15];
  const float* fcb  = (const float*)d_in[16];
  float* out = (float*)d_out;

  const int N = in_sizes[0] / 128;
  const int E = in_sizes[1] / 2;
  const int G = out_size;
  const int NB = (N + 255) >> 8;

  char* p = (char*)d_ws;
  auto alloc = [&](size_t bytes) -> void* {
    void* r = (void*)p;
    p += (bytes + 255) & ~(size_t)255;
    return r;
  };
  ushort* bufH   = (ushort*)alloc((size_t)N*128*sizeof(ushort));  // GEMM out (bf16)
  ushort* aggB   = (ushort*)alloc((size_t)N*128*sizeof(ushort));  // agg out L1/L2 (bf16)
  float*  bufA32 = (float*)alloc((size_t)N*32*sizeof(float));     // agg out L3 (fp32)
  float*  asrc   = (float*)alloc((size_t)N*4*sizeof(float));
  float*  adst   = (float*)alloc((size_t)N*4*sizeof(float));
  int*    offsets= (int*)alloc((size_t)(N+1)*sizeof(int));
  int*    csr    = (int*)alloc((size_t)E*sizeof(int));
  uint*   tmp    = (uint*)alloc((size_t)E*sizeof(uint));
  int*    bCount = (int*)alloc(512*sizeof(int));
  int*    bBase  = (int*)alloc(520*sizeof(int));
  int*    gcursor= (int*)alloc(512*sizeof(int));
  int*    gstart = (int*)alloc((size_t)(G+1)*sizeof(int));
  ushort* Wf1    = (ushort*)alloc(8*4*64*8*sizeof(ushort));
  ushort* Wf2    = (ushort*)alloc(8*4*64*8*sizeof(ushort));
  ushort* Wf3    = (ushort*)alloc(2*4*64*8*sizeof(ushort));

  hipMemsetAsync(bCount, 0, 512*sizeof(int), stream);

  // W repacks (independent, cheap)
  k_wrep<8><<<8, 256, 0, stream>>>(W1, Wf1);
  k_wrep<8><<<8, 256, 0, stream>>>(W2, Wf2);
  k_wrep<2><<<2, 256, 0, stream>>>(W3, Wf3);

  // CSR build
  k_histA<<<(E+2047)/2048, 256, 0, stream>>>(ei, E, bCount);
  k_scanB<<<1, 256, 0, stream>>>(bCount, NB, bBase, gcursor, E);
  k_scatA<<<(E+CHUNK-1)/CHUNK, 256, 0, stream>>>(ei, E, NB, gcursor, tmp);
  k_csr<<<NB, 256, 0, stream>>>(tmp, bBase, N, NB, offsets, csr);
  k_bounds<<<(N+255)/256, 256, 0, stream>>>(batch, N, G, gstart);

  const int GB = 512;
  const int NWB = (N + 3)/4;      // fused agg128: 4 nodes/block (1 per wave)
  const int NWB32 = (N + 15)/16;  // agg32: 16 nodes/block (4 per wave)
  // layer 1
  k_mgemm<8, true ><<<GB, 256, 0, stream>>>(x, Wf1, bufH, N);
  k_attn<<<(N*4+255)/256, 256, 0, stream>>>(bufH, as1, ad1, asrc, adst, N, 4, 128);
  k_agg128f<true><<<NWB, 256, 0, stream>>>(bufH, asrc, adst, offsets, csr, b1, aggB, N);
  // layer 2
  k_mgemm<8, false><<<GB, 256, 0, stream>>>(aggB, Wf2, bufH, N);
  k_attn<<<(N*4+255)/256, 256, 0, stream>>>(bufH, as2, ad2, asrc, adst, N, 4, 128);
  k_agg128f<true><<<NWB, 256, 0, stream>>>(bufH, asrc, adst, offsets, csr, b2, aggB, N);
  // layer 3
  k_mgemm<2, false><<<GB, 256, 0, stream>>>(aggB, Wf3, bufH, N);
  k_attn<<<(N+255)/256, 256, 0, stream>>>(bufH, as3, ad3, asrc, adst, N, 1, 32);
  k_agg32<<<NWB32, 256, 0, stream>>>(bufH, asrc, adst, offsets, csr, b3, bufA32, N);
  // readout
  k_pool2<<<G, 256, 0, stream>>>(bufA32, gstart, fcw, fcb, out, G);
}